// Round 12
// baseline (470.614 us; speedup 1.0000x reference)
//
#include <hip/hip_runtime.h>
#include <cstdint>

// ShortTermLSTM on MI355X: batched LSTM, transposed-GEMM f16 MFMA, cell fully
// in registers, fused-rcp activations in the exp2 domain.
// R1 569us baseline; R4 444 (x prefetch); R5 370 (h f16); R8 336 (transposed
// GEMM, cell in regs); R9 322 unstable; R10 324/292 steady (write fence);
// R11 321/296 (reg-quantum hypothesis dead: 140 regs, occupancy still 26%).
// R12: (a) 5-WAVE BLOCKS (320 thr): 25 tiles / 5 waves = 5/wave, perfectly
//   balanced — removes wave0's +1 docell from every step's critical path;
//   (b) exp2-domain: W/b rows pre-scaled by log2e (i,f,o) and 2log2e (g),
//   c kept in 2log2e domain -> all exps are bare v_exp_f32, -5 muls/cell.
//
// A[16][128] per step (ping-pong LDS):
//   k  0.. 99: f16(h)      -> W = f16(W_hh * s)        s=log2e (2log2e for g rows)
//   k100..103: x_hi        -> W = hi(W_ih * s)
//   k104..107: x_lo        -> W = hi(W_ih * s) (copy)
//   k108..111: x_hi        -> W = f16(W_ih*s - hi)
//   k112     : 1.0         -> W = hi((b_ih+b_hh)*s)
//   k113     : 1.0         -> W = f16(b*s - hi)
//   k114..127: 0
// Residual error: dropped h*W_hh_lo (~6e-5/step); measured margin ~4x.

#define H_UNITS 100
#define T_STEPS 128
#define S_BLK   16
#define NSEQ    12288
#define NBLK    (NSEQ / S_BLK)   // 768
#define NTILE   25               // 100 units / 4 per tile
#define KSTR    136              // LDS h row stride (ushorts): 8-phase-ideal b128 reads
#define NTHR    320              // 5 waves
#define LOG2E   1.4426950408889634f

typedef __attribute__((ext_vector_type(8))) _Float16 halfx8;
typedef __attribute__((ext_vector_type(8))) unsigned short ushortx8;
typedef __attribute__((ext_vector_type(4))) float floatx4;

__device__ __forceinline__ unsigned short f32_to_f16u(float x) {
    _Float16 h = (_Float16)x;                       // v_cvt_f16_f32 (RNE)
    return __builtin_bit_cast(unsigned short, h);
}
__device__ __forceinline__ float f16u_to_f32(unsigned short u) {
    _Float16 h = __builtin_bit_cast(_Float16, u);
    return (float)h;
}

// ---------------------------------------------------------------------------
// Prep: pack W (pre-scaled into exp2 domain) into MFMA A-operand fragment
// order with gate-interleaved rows:
//   frag elem (tile,kc,lane,j) = Wsc[row = (m&3)*100 + tile*4 + (m>>2)][k]
//   k = kc*32 + quad*8 + j, m = lane&15, quad = (lane>>4)&3.
// ---------------------------------------------------------------------------
__global__ void lstm_prep_pack(const float* __restrict__ W_ih,
                               const float* __restrict__ W_hh,
                               const float* __restrict__ b_ih,
                               const float* __restrict__ b_hh,
                               ushortx8* __restrict__ Bpack) {
    int t = blockIdx.x * 256 + threadIdx.x;   // (tile,kc,lane) flattened: 25*4*64 = 6400
    if (t >= NTILE * 4 * 64) return;
    int lane = t & 63;
    int kc   = (t >> 6) & 3;
    int tile = t >> 8;
    int m    = lane & 15;
    int n  = (m & 3) * 100 + tile * 4 + (m >> 2);   // permuted gate row (i,f,g,o = m&3)
    float sc = (n >= 200 && n < 300) ? (2.0f * LOG2E) : LOG2E;   // g rows get 2x
    int k0 = kc * 32 + ((lane >> 4) & 3) * 8;
    ushortx8 v;
#pragma unroll
    for (int j = 0; j < 8; ++j) {
        int k = k0 + j;
        unsigned short w = 0;
        if (k < 100) {
            w = f32_to_f16u(W_hh[n * 100 + k] * sc);
        } else if (k < 108) {                     // k100-103 AND k104-107: hi(W_ih*sc)
            w = f32_to_f16u(W_ih[n * 4 + ((k - 100) & 3)] * sc);
        } else if (k < 112) {                     // k108-111: lo(W_ih*sc)
            float wf = W_ih[n * 4 + (k - 108)] * sc;
            unsigned short hi = f32_to_f16u(wf);
            w = f32_to_f16u(wf - f16u_to_f32(hi));
        } else if (k == 112) {                    // b_hi (scaled)
            float b = (b_ih[n] + b_hh[n]) * sc;
            w = f32_to_f16u(b);
        } else if (k == 113) {                    // b_lo (scaled)
            float b = (b_ih[n] + b_hh[n]) * sc;
            unsigned short hi = f32_to_f16u(b);
            w = f32_to_f16u(b - f16u_to_f32(hi));
        }
        v[j] = w;
    }
    Bpack[t] = v;
}

// ---------------------------------------------------------------------------
// Main: one block = 16 sequences, full T loop. 5 waves; wave w owns tiles
// {w, w+5, w+10, w+15, w+20} — exactly 5 each, branch-free, balanced.
// Lane cell: unit j = tile*4 + quad, seq s = lane&15, acc = {i,f,g,o} in the
// exp2 domain. W kc1..3 in regs (60); kc0 in LDS. Two barriers per step.
// ---------------------------------------------------------------------------
__global__ void __launch_bounds__(NTHR, 3)
lstm_main(const float* __restrict__ x, const ushortx8* __restrict__ Bpack,
          float* __restrict__ out) {
    __shared__ __align__(16) unsigned short s_A[2][16 * KSTR];   // ping-pong, 2 x 4352 B
    __shared__ __align__(16) ushortx8       s_W[NTILE * 64];     // 25600 B, kc0 W-frags

    const int tid  = threadIdx.x;
    const int lane = tid & 63;
    const int wave = tid >> 6;    // 0..4
    const int seq0 = blockIdx.x * S_BLK;
    const int m    = lane & 15;
    const int quad = lane >> 4;

    // ---- W fragments kc1..3 of this wave's 5 tiles: global -> regs (60)
    halfx8 wfrag[5][3];
#pragma unroll
    for (int it = 0; it < 5; ++it) {
        int tile = wave + it * 5;
#pragma unroll
        for (int kc = 0; kc < 3; ++kc)
            wfrag[it][kc] = __builtin_bit_cast(halfx8, Bpack[(tile * 4 + kc + 1) * 64 + lane]);
    }
    // ---- kc0 frags (all tiles): global -> LDS, once
    for (int i = tid; i < NTILE * 64; i += NTHR)
        s_W[i] = Bpack[(i >> 6) * 256 + (i & 63)];

    // refresh-thread x pointer (valid for tid < 128): (s = tid&15, cc = tid>>4)
    const int rs = tid & 15, rc = tid >> 4;
    const float* xb = x + (size_t)(seq0 + rs) * (T_STEPS * 4) + (rc & 3);

    // ---- zero both buffers (h(0)=0; k114-127 stay 0 forever)
    for (int i = tid; i < (2 * 16 * KSTR) / 2; i += NTHR)
        ((unsigned int*)s_A)[i] = 0u;
    float x0 = 0.0f;
    if (tid < 128) x0 = xb[0];
    __syncthreads();
    // ---- x(t=0) into buf0; constant bias-select cols into BOTH buffers
    if (tid < 128) {
        if (rc < 4) {
            unsigned short hi = f32_to_f16u(x0);
            s_A[0][rs * KSTR + 100 + rc] = hi;    // x_hi (W_hi route)
            s_A[0][rs * KSTR + 108 + rc] = hi;    // x_hi (W_lo route)
        } else {
            float xv = x0;
            unsigned short hi = f32_to_f16u(xv);
            s_A[0][rs * KSTR + 104 + (rc - 4)] = f32_to_f16u(xv - f16u_to_f32(hi)); // x_lo
        }
    } else if (tid < 160) {
        int d = tid - 128;                     // (buf, s) for k=112
        s_A[d >> 4][(d & 15) * KSTR + 112] = 0x3C00;
    } else if (tid < 192) {
        int d = tid - 160;                     // (buf, s) for k=113
        s_A[d >> 4][(d & 15) * KSTR + 113] = 0x3C00;
    }

    float c_reg[5];   // cell state in 2*log2e domain
#pragma unroll
    for (int it = 0; it < 5; ++it) c_reg[it] = 0.0f;

    const int aOff = m * KSTR + quad * 8;

    for (int t = 0; t < T_STEPS; ++t) {
        const int bR = t & 1;
        // prefetch x(t+1) — issued before MFMA phase to hide latency
        float xnext = 0.0f;
        if (tid < 128) {
            int tn = t + 1; if (tn > T_STEPS - 1) tn = T_STEPS - 1;
            xnext = xb[tn * 4];
        }
        __syncthreads();   // barrier 1: buf[bR] (h(t), x(t)) ready

        const unsigned short* base  = s_A[bR];
        unsigned short*       baseW = s_A[bR ^ 1];
        halfx8 hh[4];
#pragma unroll
        for (int kc = 0; kc < 4; ++kc)
            hh[kc] = *(const halfx8*)(base + aOff + kc * 32);   // ds_read_b128

        const bool last = (t == T_STEPS - 1);

#pragma unroll
        for (int it = 0; it < 5; ++it) {
            int tile = wave + it * 5;
            halfx8 w0 = __builtin_bit_cast(halfx8, s_W[tile * 64 + lane]);  // kc0 frag
            floatx4 acc = {0.0f, 0.0f, 0.0f, 0.0f};
            acc = __builtin_amdgcn_mfma_f32_16x16x32_f16(w0,           hh[0], acc, 0, 0, 0);
            acc = __builtin_amdgcn_mfma_f32_16x16x32_f16(wfrag[it][0], hh[1], acc, 0, 0, 0);
            acc = __builtin_amdgcn_mfma_f32_16x16x32_f16(wfrag[it][1], hh[2], acc, 0, 0, 0);
            acc = __builtin_amdgcn_mfma_f32_16x16x32_f16(wfrag[it][2], hh[3], acc, 0, 0, 0);
            // lane = (seq s=m, unit j=tile*4+quad); acc = {i,f,g,o} * log2e
            // (g row pre-scaled by 2log2e). Fused-rcp cell, exp2 domain:
            float ei = exp2f(acc[0]);            // e^i
            float ef = exp2f(acc[1]);            // e^f
            float eg = exp2f(acc[2]);            // e^{2g}
            float eo = exp2f(acc[3]);            // e^o
            float a  = 1.0f + ei, b = 1.0f + ef;
            float d  = eg + 1.0f, e2 = eg - 1.0f;
            float q  = a * d;
            float r  = __builtin_amdgcn_rcpf(q * b);
            // c2 = (2log2e)*c: c2' = sigm(f)*c2 + (2log2e)*sigm(i)*tanh(g)
            float nm = fmaf(ef * q, c_reg[it], (ei * b * (2.0f * LOG2E)) * e2);
            float c2 = nm * r;
            c_reg[it] = c2;
            float cc = fminf(c2, 115.0f);        // exp2 overflow guard
            float ec = exp2f(cc);                // e^{2c}
            float r2 = __builtin_amdgcn_rcpf((1.0f + eo) * (ec + 1.0f));
            float h  = (eo * (ec - 1.0f)) * r2;
            int j = tile * 4 + quad;
            if (!last) {
                baseW[m * KSTR + j] = f32_to_f16u(h);    // h(t+1) f16 -> other buffer
            } else {
                out[(size_t)(seq0 + m) * H_UNITS + j] = h;
            }
        }

        if (tid < 128 && !last) {                // x(t+1) k100..111 -> other buffer
            if (rc < 4) {
                unsigned short hi = f32_to_f16u(xnext);
                baseW[rs * KSTR + 100 + rc] = hi;
                baseW[rs * KSTR + 108 + rc] = hi;
            } else {
                unsigned short hi = f32_to_f16u(xnext);
                baseW[rs * KSTR + 104 + (rc - 4)] = f32_to_f16u(xnext - f16u_to_f32(hi));
            }
        }
        __syncthreads();   // barrier 2: write-phase fence
    }
}

extern "C" void kernel_launch(void* const* d_in, const int* in_sizes, int n_in,
                              void* d_out, int out_size, void* d_ws, size_t ws_size,
                              hipStream_t stream) {
    const float* x    = (const float*)d_in[0];   // [4096,3,128,4]
    const float* W_ih = (const float*)d_in[1];   // [400,4]
    const float* W_hh = (const float*)d_in[2];   // [400,100]
    const float* b_ih = (const float*)d_in[3];   // [400]
    const float* b_hh = (const float*)d_in[4];   // [400]
    ushortx8* Bpack = (ushortx8*)d_ws;           // 25*4*64*16 B = 102,400 B

    lstm_prep_pack<<<25, 256, 0, stream>>>(W_ih, W_hh, b_ih, b_hh, Bpack);
    lstm_main<<<NBLK, NTHR, 0, stream>>>(x, Bpack, (float*)d_out);
}

// Round 13
// 389.489 us; speedup vs baseline: 1.2083x; 1.2083x over previous
//
#include <hip/hip_runtime.h>
#include <cstdint>

// ShortTermLSTM on MI355X: batched LSTM, transposed-GEMM f16 MFMA, cell fully
// in registers, fused-rcp activations in the exp2 domain.
// R1 569us baseline; R4 444 (x prefetch); R5 370 (h f16); R8 336 (transposed
// GEMM, cell in regs); R10 324/292 steady (write fence); R11 321/296
// (reg-quantum hypothesis dead: 140 regs, occupancy still ~26%).
// R12 (471/450, reverted): 5-wave blocks -> 2 waves share one SIMD, serialize,
//   barrier pins the block to the slow SIMD. Block waves must divide into 4.
//   exp2-domain math validated (absmax bit-identical) — kept.
// R13: LDS-granule hypothesis. All R4-R11 configs had LDS in (32K,64K]; if
//   LDS granule = 32KB each block charged 64KB -> hard 2-block/CU ceiling.
//   Shave LDS to 32,256 B: kc0 frags in LDS for tiles 0..22 only; tile 23/24
//   kc0 in a spare reg of wave3/wave0. Math bit-identical to R12.
//
// A[16][128] per step (ping-pong LDS):
//   k  0.. 99: f16(h)      -> W = f16(W_hh * s)    s=log2e (2log2e for g rows)
//   k100..103: x_hi        -> W = hi(W_ih * s)
//   k104..107: x_lo        -> W = hi(W_ih * s) (copy)
//   k108..111: x_hi        -> W = f16(W_ih*s - hi)
//   k112/113 : 1.0         -> W = b_hi / b_lo (scaled)
//   k114..127: 0
// Residual error: dropped h*W_hh_lo (~6e-5/step); measured margin ~4x.

#define H_UNITS 100
#define T_STEPS 128
#define S_BLK   16
#define NSEQ    12288
#define NBLK    (NSEQ / S_BLK)   // 768
#define NTILE   25               // 100 units / 4 per tile
#define KSTR    136              // LDS h row stride (ushorts): 8-phase-ideal b128 reads
#define NLDSW   23               // tiles with kc0 frag in LDS (23,552 B)
#define LOG2E   1.4426950408889634f

typedef __attribute__((ext_vector_type(8))) _Float16 halfx8;
typedef __attribute__((ext_vector_type(8))) unsigned short ushortx8;
typedef __attribute__((ext_vector_type(4))) float floatx4;

__device__ __forceinline__ unsigned short f32_to_f16u(float x) {
    _Float16 h = (_Float16)x;                       // v_cvt_f16_f32 (RNE)
    return __builtin_bit_cast(unsigned short, h);
}
__device__ __forceinline__ float f16u_to_f32(unsigned short u) {
    _Float16 h = __builtin_bit_cast(_Float16, u);
    return (float)h;
}

// ---------------------------------------------------------------------------
// Prep: pack W (pre-scaled into exp2 domain) into MFMA A-operand fragment
// order with gate-interleaved rows:
//   frag elem (tile,kc,lane,j) = Wsc[row = (m&3)*100 + tile*4 + (m>>2)][k]
//   k = kc*32 + quad*8 + j, m = lane&15, quad = (lane>>4)&3.
// ---------------------------------------------------------------------------
__global__ void lstm_prep_pack(const float* __restrict__ W_ih,
                               const float* __restrict__ W_hh,
                               const float* __restrict__ b_ih,
                               const float* __restrict__ b_hh,
                               ushortx8* __restrict__ Bpack) {
    int t = blockIdx.x * 256 + threadIdx.x;   // (tile,kc,lane) flattened: 25*4*64 = 6400
    if (t >= NTILE * 4 * 64) return;
    int lane = t & 63;
    int kc   = (t >> 6) & 3;
    int tile = t >> 8;
    int m    = lane & 15;
    int n  = (m & 3) * 100 + tile * 4 + (m >> 2);   // permuted gate row (i,f,g,o = m&3)
    float sc = (n >= 200 && n < 300) ? (2.0f * LOG2E) : LOG2E;   // g rows get 2x
    int k0 = kc * 32 + ((lane >> 4) & 3) * 8;
    ushortx8 v;
#pragma unroll
    for (int j = 0; j < 8; ++j) {
        int k = k0 + j;
        unsigned short w = 0;
        if (k < 100) {
            w = f32_to_f16u(W_hh[n * 100 + k] * sc);
        } else if (k < 108) {                     // k100-103 AND k104-107: hi(W_ih*sc)
            w = f32_to_f16u(W_ih[n * 4 + ((k - 100) & 3)] * sc);
        } else if (k < 112) {                     // k108-111: lo(W_ih*sc)
            float wf = W_ih[n * 4 + (k - 108)] * sc;
            unsigned short hi = f32_to_f16u(wf);
            w = f32_to_f16u(wf - f16u_to_f32(hi));
        } else if (k == 112) {                    // b_hi (scaled)
            float b = (b_ih[n] + b_hh[n]) * sc;
            w = f32_to_f16u(b);
        } else if (k == 113) {                    // b_lo (scaled)
            float b = (b_ih[n] + b_hh[n]) * sc;
            unsigned short hi = f32_to_f16u(b);
            w = f32_to_f16u(b - f16u_to_f32(hi));
        }
        v[j] = w;
    }
    Bpack[t] = v;
}

// ---------------------------------------------------------------------------
// Main: one block = 16 sequences, full T loop. 4 waves; waves do tiles
// {w, w+4, ..., w+20} branch-free, wave0 additionally tile 24.
// Lane cell: unit j = tile*4 + quad, seq s = lane&15, acc = {i,f,g,o} in the
// exp2 domain. W kc1..3 in regs (84); kc0 tiles 0..22 in LDS, tile 23 (wave3)
// and 24 (wave0) in a spare reg. Two barriers per step. LDS 32,256 B.
// ---------------------------------------------------------------------------
__global__ void __launch_bounds__(256, 3)
lstm_main(const float* __restrict__ x, const ushortx8* __restrict__ Bpack,
          float* __restrict__ out) {
    __shared__ __align__(16) unsigned short s_A[2][16 * KSTR];   // ping-pong, 2 x 4352 B
    __shared__ __align__(16) ushortx8       s_W[NLDSW * 64];     // 23552 B, kc0 W-frags

    const int tid  = threadIdx.x;
    const int lane = tid & 63;
    const int wave = tid >> 6;    // 0..3
    const int seq0 = blockIdx.x * S_BLK;
    const int m    = lane & 15;
    const int quad = lane >> 4;

    // ---- W fragments kc1..3: global -> regs, once (84 regs/wave)
    halfx8 wfrag[7][3];
#pragma unroll
    for (int it = 0; it < 7; ++it) {
        int tile = wave + it * 4;
        if (tile < NTILE) {
#pragma unroll
            for (int kc = 0; kc < 3; ++kc)
                wfrag[it][kc] = __builtin_bit_cast(halfx8, Bpack[(tile * 4 + kc + 1) * 64 + lane]);
        }
    }
    // ---- special kc0 frag: wave3 -> tile 23, wave0 (and others, unused) -> tile 24
    const int spTile = (wave == 3) ? 23 : 24;
    halfx8 w0sp = __builtin_bit_cast(halfx8, Bpack[(spTile * 4) * 64 + lane]);
    // ---- kc0 frags tiles 0..22: global -> LDS, once
    for (int i = tid; i < NLDSW * 64; i += 256)
        s_W[i] = Bpack[(i >> 6) * 256 + (i & 63)];

    // refresh-thread x pointer (valid for tid < 128): (s = tid&15, cc = tid>>4)
    const int rs = tid & 15, rc = tid >> 4;
    const float* xb = x + (size_t)(seq0 + rs) * (T_STEPS * 4) + (rc & 3);

    // ---- zero both buffers (h(0)=0; k114-127 stay 0 forever)
    for (int i = tid; i < (2 * 16 * KSTR) / 2; i += 256)
        ((unsigned int*)s_A)[i] = 0u;
    float x0 = 0.0f;
    if (tid < 128) x0 = xb[0];
    __syncthreads();
    // ---- x(t=0) into buf0; constant bias-select cols into BOTH buffers
    if (tid < 128) {
        if (rc < 4) {
            unsigned short hi = f32_to_f16u(x0);
            s_A[0][rs * KSTR + 100 + rc] = hi;    // x_hi (W_hi route)
            s_A[0][rs * KSTR + 108 + rc] = hi;    // x_hi (W_lo route)
        } else {
            float xv = x0;
            unsigned short hi = f32_to_f16u(xv);
            s_A[0][rs * KSTR + 104 + (rc - 4)] = f32_to_f16u(xv - f16u_to_f32(hi)); // x_lo
        }
    } else if (tid < 160) {
        int d = tid - 128;                     // (buf, s) for k=112
        s_A[d >> 4][(d & 15) * KSTR + 112] = 0x3C00;
    } else if (tid < 192) {
        int d = tid - 160;                     // (buf, s) for k=113
        s_A[d >> 4][(d & 15) * KSTR + 113] = 0x3C00;
    }

    float c_reg[6];   // cell state in 2*log2e domain
#pragma unroll
    for (int it = 0; it < 6; ++it) c_reg[it] = 0.0f;
    float c24 = 0.0f;

    const int aOff = m * KSTR + quad * 8;

    for (int t = 0; t < T_STEPS; ++t) {
        const int bR = t & 1;
        // prefetch x(t+1) — issued before MFMA phase to hide latency
        float xnext = 0.0f;
        if (tid < 128) {
            int tn = t + 1; if (tn > T_STEPS - 1) tn = T_STEPS - 1;
            xnext = xb[tn * 4];
        }
        __syncthreads();   // barrier 1: buf[bR] (h(t), x(t)) ready

        const unsigned short* base  = s_A[bR];
        unsigned short*       baseW = s_A[bR ^ 1];
        halfx8 hh[4];
#pragma unroll
        for (int kc = 0; kc < 4; ++kc)
            hh[kc] = *(const halfx8*)(base + aOff + kc * 32);   // ds_read_b128

        const bool last = (t == T_STEPS - 1);

        auto docell = [&](int tile, halfx8 w0, halfx8 w1, halfx8 w2, halfx8 w3, float& cm) {
            floatx4 acc = {0.0f, 0.0f, 0.0f, 0.0f};
            acc = __builtin_amdgcn_mfma_f32_16x16x32_f16(w0, hh[0], acc, 0, 0, 0);
            acc = __builtin_amdgcn_mfma_f32_16x16x32_f16(w1, hh[1], acc, 0, 0, 0);
            acc = __builtin_amdgcn_mfma_f32_16x16x32_f16(w2, hh[2], acc, 0, 0, 0);
            acc = __builtin_amdgcn_mfma_f32_16x16x32_f16(w3, hh[3], acc, 0, 0, 0);
            // lane = (seq s=m, unit j=tile*4+quad); acc = {i,f,g,o} in exp2 dom.
            float ei = exp2f(acc[0]);            // e^i
            float ef = exp2f(acc[1]);            // e^f
            float eg = exp2f(acc[2]);            // e^{2g}
            float eo = exp2f(acc[3]);            // e^o
            float a  = 1.0f + ei, b = 1.0f + ef;
            float d  = eg + 1.0f, e2 = eg - 1.0f;
            float q  = a * d;
            float r  = __builtin_amdgcn_rcpf(q * b);
            // c2 = (2log2e)*c
            float nm = fmaf(ef * q, cm, (ei * b * (2.0f * LOG2E)) * e2);
            float c2 = nm * r;
            cm = c2;
            float cc = fminf(c2, 115.0f);        // exp2 overflow guard
            float ec = exp2f(cc);                // e^{2c}
            float r2 = __builtin_amdgcn_rcpf((1.0f + eo) * (ec + 1.0f));
            float h  = (eo * (ec - 1.0f)) * r2;
            int j = tile * 4 + quad;
            if (!last) {
                baseW[m * KSTR + j] = f32_to_f16u(h);    // h(t+1) f16 -> other buffer
            } else {
                out[(size_t)(seq0 + m) * H_UNITS + j] = h;
            }
        };

#pragma unroll
        for (int it = 0; it < 6; ++it) {         // tiles 0..23: branch-free
            int tile = wave + it * 4;
            halfx8 w0;
            if (it < 5) {
                w0 = __builtin_bit_cast(halfx8, s_W[tile * 64 + lane]);          // tile <= 18+w < 23
            } else {
                int tl = tile < NLDSW ? tile : NLDSW - 1;                        // clamp (wave3: discarded)
                halfx8 wl = __builtin_bit_cast(halfx8, s_W[tl * 64 + lane]);
                w0 = (wave == 3) ? w0sp : wl;                                    // tile 23 from reg
            }
            docell(tile, w0, wfrag[it][0], wfrag[it][1], wfrag[it][2], c_reg[it]);
        }
        if (wave == 0)                           // tile 24: wave0 only, kc0 from reg
            docell(24, w0sp, wfrag[6][0], wfrag[6][1], wfrag[6][2], c24);

        if (tid < 128 && !last) {                // x(t+1) k100..111 -> other buffer
            if (rc < 4) {
                unsigned short hi = f32_to_f16u(xnext);
                baseW[rs * KSTR + 100 + rc] = hi;
                baseW[rs * KSTR + 108 + rc] = hi;
            } else {
                unsigned short hi = f32_to_f16u(xnext);
                baseW[rs * KSTR + 104 + (rc - 4)] = f32_to_f16u(xnext - f16u_to_f32(hi));
            }
        }
        __syncthreads();   // barrier 2: write-phase fence
    }
}

extern "C" void kernel_launch(void* const* d_in, const int* in_sizes, int n_in,
                              void* d_out, int out_size, void* d_ws, size_t ws_size,
                              hipStream_t stream) {
    const float* x    = (const float*)d_in[0];   // [4096,3,128,4]
    const float* W_ih = (const float*)d_in[1];   // [400,4]
    const float* W_hh = (const float*)d_in[2];   // [400,100]
    const float* b_ih = (const float*)d_in[3];   // [400]
    const float* b_hh = (const float*)d_in[4];   // [400]
    ushortx8* Bpack = (ushortx8*)d_ws;           // 25*4*64*16 B = 102,400 B

    lstm_prep_pack<<<25, 256, 0, stream>>>(W_ih, W_hh, b_ih, b_hh, Bpack);
    lstm_main<<<NBLK, 256, 0, stream>>>(x, Bpack, (float*)d_out);
}

// Round 14
// 289.443 us; speedup vs baseline: 1.6259x; 1.3457x over previous
//
#include <hip/hip_runtime.h>
#include <cstdint>

// ShortTermLSTM on MI355X: batched LSTM, transposed-GEMM f16 MFMA, cell fully
// in registers, fused-rcp activations in the exp2 domain (raw v_exp_f32).
// R1 569us baseline; R4 444; R5 370; R8 336 (transposed GEMM, cell in regs);
// R10 324/292 steady (write fence) — best structure.
// R11-R13 falsified all residency hypotheses: occupancy pinned at 8 waves/CU
//   (2 blocks x 4 waves) regardless of regs (140..196), LDS (32.2K..50K),
//   and geometry (5-wave blocks regressed: waves must divide into 4 SIMDs).
// R13 also showed exp2f LIBCALL costs ~+86us VALU vs __expf (edge-case code).
// R14: R10 structure + exp2-pre-scaled weights + __builtin_amdgcn_exp2f
//   (bare v_exp_f32; __has_builtin-guarded) -> -6 VALU ops/cell, no libcall.
//   x-refresh moved to waves 2/3 (wave0 already carries the 7th docell).
//
// A[16][128] per step (ping-pong LDS):
//   k  0.. 99: f16(h)      -> W = f16(W_hh * s)    s=log2e (2log2e for g rows)
//   k100..103: x_hi        -> W = hi(W_ih * s)
//   k104..107: x_lo        -> W = hi(W_ih * s) (copy)
//   k108..111: x_hi        -> W = f16(W_ih*s - hi)
//   k112/113 : 1.0         -> W = b_hi / b_lo (scaled)
//   k114..127: 0
// Residual error: dropped h*W_hh_lo (~6e-5/step); measured margin ~4x.

#define H_UNITS 100
#define T_STEPS 128
#define S_BLK   16
#define NSEQ    12288
#define NBLK    (NSEQ / S_BLK)   // 768
#define NTILE   25               // 100 units / 4 per tile
#define KSTR    136              // LDS h row stride (ushorts): 8-phase-ideal b128 reads
#define LOG2E   1.4426950408889634f

typedef __attribute__((ext_vector_type(8))) _Float16 halfx8;
typedef __attribute__((ext_vector_type(8))) unsigned short ushortx8;
typedef __attribute__((ext_vector_type(4))) float floatx4;

__device__ __forceinline__ unsigned short f32_to_f16u(float x) {
    _Float16 h = (_Float16)x;                       // v_cvt_f16_f32 (RNE)
    return __builtin_bit_cast(unsigned short, h);
}
__device__ __forceinline__ float f16u_to_f32(unsigned short u) {
    _Float16 h = __builtin_bit_cast(_Float16, u);
    return (float)h;
}
#if __has_builtin(__builtin_amdgcn_exp2f)
__device__ __forceinline__ float fexp2(float x) { return __builtin_amdgcn_exp2f(x); }
#else
__device__ __forceinline__ float fexp2(float x) { return exp2f(x); }
#endif

// ---------------------------------------------------------------------------
// Prep: pack W (pre-scaled into exp2 domain) into MFMA A-operand fragment
// order with gate-interleaved rows:
//   frag elem (tile,kc,lane,j) = Wsc[row = (m&3)*100 + tile*4 + (m>>2)][k]
//   k = kc*32 + quad*8 + j, m = lane&15, quad = (lane>>4)&3.
// ---------------------------------------------------------------------------
__global__ void lstm_prep_pack(const float* __restrict__ W_ih,
                               const float* __restrict__ W_hh,
                               const float* __restrict__ b_ih,
                               const float* __restrict__ b_hh,
                               ushortx8* __restrict__ Bpack) {
    int t = blockIdx.x * 256 + threadIdx.x;   // (tile,kc,lane) flattened: 25*4*64 = 6400
    if (t >= NTILE * 4 * 64) return;
    int lane = t & 63;
    int kc   = (t >> 6) & 3;
    int tile = t >> 8;
    int m    = lane & 15;
    int n  = (m & 3) * 100 + tile * 4 + (m >> 2);   // permuted gate row (i,f,g,o = m&3)
    float sc = (n >= 200 && n < 300) ? (2.0f * LOG2E) : LOG2E;   // g rows get 2x
    int k0 = kc * 32 + ((lane >> 4) & 3) * 8;
    ushortx8 v;
#pragma unroll
    for (int j = 0; j < 8; ++j) {
        int k = k0 + j;
        unsigned short w = 0;
        if (k < 100) {
            w = f32_to_f16u(W_hh[n * 100 + k] * sc);
        } else if (k < 108) {                     // k100-103 AND k104-107: hi(W_ih*sc)
            w = f32_to_f16u(W_ih[n * 4 + ((k - 100) & 3)] * sc);
        } else if (k < 112) {                     // k108-111: lo(W_ih*sc)
            float wf = W_ih[n * 4 + (k - 108)] * sc;
            unsigned short hi = f32_to_f16u(wf);
            w = f32_to_f16u(wf - f16u_to_f32(hi));
        } else if (k == 112) {                    // b_hi (scaled)
            float b = (b_ih[n] + b_hh[n]) * sc;
            w = f32_to_f16u(b);
        } else if (k == 113) {                    // b_lo (scaled)
            float b = (b_ih[n] + b_hh[n]) * sc;
            unsigned short hi = f32_to_f16u(b);
            w = f32_to_f16u(b - f16u_to_f32(hi));
        }
        v[j] = w;
    }
    Bpack[t] = v;
}

// ---------------------------------------------------------------------------
// Main: one block = 16 sequences, full T loop. 4 waves; waves do tiles
// {w, w+4, ..., w+20}, wave0 additionally tile 24. Lane cell: unit
// j = tile*4 + quad, seq s = lane&15, acc = {i,f,g,o} in the exp2 domain.
// W kc1..3 in regs (84); kc0 in LDS. Two barriers per step. LDS 34,304 B.
// x-refresh on waves 2/3 (wave0 carries the extra docell).
// ---------------------------------------------------------------------------
__global__ void __launch_bounds__(256, 3)
lstm_main(const float* __restrict__ x, const ushortx8* __restrict__ Bpack,
          float* __restrict__ out) {
    __shared__ __align__(16) unsigned short s_A[2][16 * KSTR];   // ping-pong, 2 x 4352 B
    __shared__ __align__(16) ushortx8       s_W[NTILE * 64];     // 25600 B, kc0 W-frags

    const int tid  = threadIdx.x;
    const int lane = tid & 63;
    const int wave = tid >> 6;    // 0..3
    const int seq0 = blockIdx.x * S_BLK;
    const int m    = lane & 15;
    const int quad = lane >> 4;

    // ---- W fragments kc1..3: global -> regs, once (84 regs/wave)
    halfx8 wfrag[7][3];
#pragma unroll
    for (int it = 0; it < 7; ++it) {
        int tile = wave + it * 4;
        if (tile < NTILE) {
#pragma unroll
            for (int kc = 0; kc < 3; ++kc)
                wfrag[it][kc] = __builtin_bit_cast(halfx8, Bpack[(tile * 4 + kc + 1) * 64 + lane]);
        }
    }
    // ---- kc0 frags (all tiles): global -> LDS, once
    for (int i = tid; i < NTILE * 64; i += 256)
        s_W[i] = Bpack[(i >> 6) * 256 + (i & 63)];

    // refresh-thread x pointer (valid for tid >= 128): (s = rt&15, cc = rt>>4)
    const int rt = tid - 128;
    const int rs = rt & 15, rc = (rt >> 4) & 7;
    const float* xb = x + (size_t)(seq0 + rs) * (T_STEPS * 4) + (rc & 3);

    // ---- zero both buffers (h(0)=0; k114-127 stay 0 forever)
    for (int i = tid; i < (2 * 16 * KSTR) / 2; i += 256)
        ((unsigned int*)s_A)[i] = 0u;
    float x0 = 0.0f;
    if (tid >= 128) x0 = xb[0];
    __syncthreads();
    // ---- x(t=0) into buf0; constant bias-select cols into BOTH buffers
    if (tid >= 128) {
        if (rc < 4) {
            unsigned short hi = f32_to_f16u(x0);
            s_A[0][rs * KSTR + 100 + rc] = hi;    // x_hi (W_hi route)
            s_A[0][rs * KSTR + 108 + rc] = hi;    // x_hi (W_lo route)
        } else {
            unsigned short hi = f32_to_f16u(x0);
            s_A[0][rs * KSTR + 104 + (rc - 4)] = f32_to_f16u(x0 - f16u_to_f32(hi)); // x_lo
        }
    } else if (tid < 32) {
        s_A[tid >> 4][(tid & 15) * KSTR + 112] = 0x3C00;   // k112 = 1.0, both bufs
    } else if (tid < 64) {
        int d = tid - 32;
        s_A[d >> 4][(d & 15) * KSTR + 113] = 0x3C00;       // k113 = 1.0, both bufs
    }

    float c_reg[6];   // cell state in 2*log2e domain
#pragma unroll
    for (int it = 0; it < 6; ++it) c_reg[it] = 0.0f;
    float c24 = 0.0f;

    const int aOff = m * KSTR + quad * 8;

    for (int t = 0; t < T_STEPS; ++t) {
        const int bR = t & 1;
        // prefetch x(t+1) — issued before MFMA phase to hide latency
        float xnext = 0.0f;
        if (tid >= 128) {
            int tn = t + 1; if (tn > T_STEPS - 1) tn = T_STEPS - 1;
            xnext = xb[tn * 4];
        }
        __syncthreads();   // barrier 1: buf[bR] (h(t), x(t)) ready

        const unsigned short* base  = s_A[bR];
        unsigned short*       baseW = s_A[bR ^ 1];
        halfx8 hh[4];
#pragma unroll
        for (int kc = 0; kc < 4; ++kc)
            hh[kc] = *(const halfx8*)(base + aOff + kc * 32);   // ds_read_b128

        const bool last = (t == T_STEPS - 1);

        auto docell = [&](int tile, halfx8 w1, halfx8 w2, halfx8 w3, float& cm) {
            halfx8 w0 = __builtin_bit_cast(halfx8, s_W[tile * 64 + lane]);  // kc0 frag
            floatx4 acc = {0.0f, 0.0f, 0.0f, 0.0f};
            acc = __builtin_amdgcn_mfma_f32_16x16x32_f16(w0, hh[0], acc, 0, 0, 0);
            acc = __builtin_amdgcn_mfma_f32_16x16x32_f16(w1, hh[1], acc, 0, 0, 0);
            acc = __builtin_amdgcn_mfma_f32_16x16x32_f16(w2, hh[2], acc, 0, 0, 0);
            acc = __builtin_amdgcn_mfma_f32_16x16x32_f16(w3, hh[3], acc, 0, 0, 0);
            // lane = (seq s=m, unit j=tile*4+quad); acc = {i,f,g,o}, exp2 dom.
            float ei = fexp2(acc[0]);            // e^i
            float ef = fexp2(acc[1]);            // e^f
            float eg = fexp2(acc[2]);            // e^{2g}
            float eo = fexp2(acc[3]);            // e^o
            float a  = 1.0f + ei, b = 1.0f + ef;
            float d  = eg + 1.0f, e2 = eg - 1.0f;
            float q  = a * d;
            float r  = __builtin_amdgcn_rcpf(q * b);
            // c2 = (2log2e)*c: c2' = sigm(f)*c2 + (2log2e)*sigm(i)*tanh(g)
            float nm = fmaf(ef * q, cm, (ei * b * (2.0f * LOG2E)) * e2);
            float c2 = nm * r;
            cm = c2;
            float cc = fminf(c2, 115.0f);        // exp2 overflow guard
            float ec = fexp2(cc);                // e^{2c}
            float r2 = __builtin_amdgcn_rcpf((1.0f + eo) * (ec + 1.0f));
            float h  = (eo * (ec - 1.0f)) * r2;
            int j = tile * 4 + quad;
            if (!last) {
                baseW[m * KSTR + j] = f32_to_f16u(h);    // h(t+1) f16 -> other buffer
            } else {
                out[(size_t)(seq0 + m) * H_UNITS + j] = h;
            }
        };

#pragma unroll
        for (int it = 0; it < 6; ++it)           // tiles 0..23: branch-free
            docell(wave + it * 4, wfrag[it][0], wfrag[it][1], wfrag[it][2], c_reg[it]);
        if (wave == 0)                           // tile 24: wave0 only
            docell(24, wfrag[6][0], wfrag[6][1], wfrag[6][2], c24);

        if (tid >= 128 && !last) {               // x(t+1) k100..111 -> other buffer
            if (rc < 4) {
                unsigned short hi = f32_to_f16u(xnext);
                baseW[rs * KSTR + 100 + rc] = hi;
                baseW[rs * KSTR + 108 + rc] = hi;
            } else {
                unsigned short hi = f32_to_f16u(xnext);
                baseW[rs * KSTR + 104 + (rc - 4)] = f32_to_f16u(xnext - f16u_to_f32(hi));
            }
        }
        __syncthreads();   // barrier 2: write-phase fence
    }
}

extern "C" void kernel_launch(void* const* d_in, const int* in_sizes, int n_in,
                              void* d_out, int out_size, void* d_ws, size_t ws_size,
                              hipStream_t stream) {
    const float* x    = (const float*)d_in[0];   // [4096,3,128,4]
    const float* W_ih = (const float*)d_in[1];   // [400,4]
    const float* W_hh = (const float*)d_in[2];   // [400,100]
    const float* b_ih = (const float*)d_in[3];   // [400]
    const float* b_hh = (const float*)d_in[4];   // [400]
    ushortx8* Bpack = (ushortx8*)d_ws;           // 25*4*64*16 B = 102,400 B

    lstm_prep_pack<<<25, 256, 0, stream>>>(W_ih, W_hh, b_ih, b_hh, Bpack);
    lstm_main<<<NBLK, 256, 0, stream>>>(x, Bpack, (float*)d_out);
}